// Round 2
// baseline (10921.354 us; speedup 1.0000x reference)
//
#include <hip/hip_runtime.h>

#define N_NODES 100000
#define N_EDGES 1600000
#define NODE_NF 11
#define EDGE_NF 4
#define H_NF 128
#define EMB_NF 4
#define SCAN_B 1024
#define NBLK ((N_NODES + SCAN_B - 1) / SCAN_B)   // 98

// ---------------------------------------------------------------------------
// Prep: transpose eW2 [k][j] -> W2T [j][k] for contiguous scalar weight rows.
// ---------------------------------------------------------------------------
__global__ __launch_bounds__(256)
void transpose_w2(const float* __restrict__ W, float* __restrict__ WT) {
    int i = blockIdx.x * 256 + threadIdx.x;
    if (i < H_NF * H_NF) {
        int k = i >> 7;
        int j = i & (H_NF - 1);
        WT[j * H_NF + k] = W[i];
    }
}

// ---------------------------------------------------------------------------
// Counting sort of edges by row (target node). hist -> scan -> permute.
// ---------------------------------------------------------------------------
__global__ __launch_bounds__(256)
void hist_kernel(const int* __restrict__ edge_index, int* hist) {
    int e = blockIdx.x * 256 + threadIdx.x;
    if (e < N_EDGES) atomicAdd(&hist[edge_index[e]], 1);
}

__global__ __launch_bounds__(SCAN_B)
void scan1_kernel(const int* __restrict__ hist, int* starts, int* bsum) {
    __shared__ int buf[SCAN_B];
    int i = blockIdx.x * SCAN_B + threadIdx.x;
    int v = (i < N_NODES) ? hist[i] : 0;
    buf[threadIdx.x] = v;
    __syncthreads();
    for (int off = 1; off < SCAN_B; off <<= 1) {
        int t = (threadIdx.x >= off) ? buf[threadIdx.x - off] : 0;
        __syncthreads();
        buf[threadIdx.x] += t;
        __syncthreads();
    }
    if (i < N_NODES) starts[i] = buf[threadIdx.x] - v;   // local exclusive
    if (threadIdx.x == SCAN_B - 1) bsum[blockIdx.x] = buf[SCAN_B - 1];
}

__global__ void scan2_kernel(int* bsum) {
    if (threadIdx.x == 0 && blockIdx.x == 0) {
        int run = 0;
        for (int b = 0; b < NBLK; ++b) { int t = bsum[b]; bsum[b] = run; run += t; }
        bsum[NBLK] = run;
    }
}

__global__ __launch_bounds__(256)
void scan3_kernel(int* starts, int* cursor, const int* __restrict__ bsum) {
    int i = blockIdx.x * 256 + threadIdx.x;
    if (i < N_NODES) {
        int s = starts[i] + bsum[i / SCAN_B];
        starts[i] = s;
        cursor[i] = s;
    }
    if (i == 0) starts[N_NODES] = bsum[NBLK];
}

__global__ __launch_bounds__(256)
void permute_kernel(const int* __restrict__ edge_index, int* cursor, int* perm) {
    int e = blockIdx.x * 256 + threadIdx.x;
    if (e < N_EDGES) {
        int pos = atomicAdd(&cursor[edge_index[e]], 1);
        perm[pos] = e;
    }
}

// ---------------------------------------------------------------------------
// Edge MLP, sorted order: slot i handles edge perm[i], writes ef[i][0:128]
// contiguously (plain streaming stores — NO float atomics).
// ---------------------------------------------------------------------------
__global__ __launch_bounds__(256)
void edge_kernel(const float* __restrict__ node_feats,
                 const int*   __restrict__ edge_index,
                 const float* __restrict__ edge_attr,
                 const float* __restrict__ eW1,
                 const float* __restrict__ eb1,
                 const float* __restrict__ W2T,
                 const float* __restrict__ eb2,
                 const int*   __restrict__ perm,
                 float* __restrict__ ef)   // [N_EDGES][H_NF], sorted order
{
    int i = blockIdx.x * 256 + threadIdx.x;
    if (i >= N_EDGES) return;
    int e = perm[i];
    int row = edge_index[e];
    int col = edge_index[N_EDGES + e];

    float h[H_NF];
    #pragma unroll
    for (int j = 0; j < H_NF; ++j) h[j] = eb1[j];

    const float* srcp = node_feats + row * NODE_NF;
    #pragma unroll 1
    for (int k = 0; k < NODE_NF; ++k) {
        float x = srcp[k];
        const float* w = eW1 + k * H_NF;
        #pragma unroll
        for (int j = 0; j < H_NF; ++j) h[j] = fmaf(x, w[j], h[j]);
    }
    const float* dstp = node_feats + col * NODE_NF;
    #pragma unroll 1
    for (int k = 0; k < NODE_NF; ++k) {
        float x = dstp[k];
        const float* w = eW1 + (NODE_NF + k) * H_NF;
        #pragma unroll
        for (int j = 0; j < H_NF; ++j) h[j] = fmaf(x, w[j], h[j]);
    }
    float4 at = ((const float4*)edge_attr)[e];
    float av[EDGE_NF] = {at.x, at.y, at.z, at.w};
    #pragma unroll
    for (int k = 0; k < EDGE_NF; ++k) {
        float x = av[k];
        const float* w = eW1 + (2 * NODE_NF + k) * H_NF;
        #pragma unroll
        for (int j = 0; j < H_NF; ++j) h[j] = fmaf(x, w[j], h[j]);
    }
    #pragma unroll
    for (int j = 0; j < H_NF; ++j) h[j] = fmaxf(h[j], 0.f);

    float* outp = ef + (size_t)i * H_NF;
    #pragma unroll 1
    for (int j0 = 0; j0 < H_NF; j0 += 8) {
        float acc[8];
        #pragma unroll
        for (int jj = 0; jj < 8; ++jj) acc[jj] = eb2[j0 + jj];
        #pragma unroll
        for (int k = 0; k < H_NF; ++k) {
            float x = h[k];
            #pragma unroll
            for (int jj = 0; jj < 8; ++jj)
                acc[jj] = fmaf(x, W2T[(j0 + jj) * H_NF + k], acc[jj]);
        }
        float4 s0 = make_float4(fmaxf(acc[0], 0.f), fmaxf(acc[1], 0.f),
                                fmaxf(acc[2], 0.f), fmaxf(acc[3], 0.f));
        float4 s1 = make_float4(fmaxf(acc[4], 0.f), fmaxf(acc[5], 0.f),
                                fmaxf(acc[6], 0.f), fmaxf(acc[7], 0.f));
        ((float4*)(outp + j0))[0] = s0;
        ((float4*)(outp + j0))[1] = s1;
    }
}

// ---------------------------------------------------------------------------
// Fallback (ws too small): atomic scatter, node-major agg.
// ---------------------------------------------------------------------------
__global__ __launch_bounds__(256)
void edge_kernel_atomic(const float* __restrict__ node_feats,
                        const int*   __restrict__ edge_index,
                        const float* __restrict__ edge_attr,
                        const float* __restrict__ eW1,
                        const float* __restrict__ eb1,
                        const float* __restrict__ W2T,
                        const float* __restrict__ eb2,
                        float* agg)   // [N_NODES][H_NF]
{
    int e = blockIdx.x * 256 + threadIdx.x;
    if (e >= N_EDGES) return;
    int row = edge_index[e];
    int col = edge_index[N_EDGES + e];

    float h[H_NF];
    #pragma unroll
    for (int j = 0; j < H_NF; ++j) h[j] = eb1[j];
    const float* srcp = node_feats + row * NODE_NF;
    #pragma unroll 1
    for (int k = 0; k < NODE_NF; ++k) {
        float x = srcp[k];
        const float* w = eW1 + k * H_NF;
        #pragma unroll
        for (int j = 0; j < H_NF; ++j) h[j] = fmaf(x, w[j], h[j]);
    }
    const float* dstp = node_feats + col * NODE_NF;
    #pragma unroll 1
    for (int k = 0; k < NODE_NF; ++k) {
        float x = dstp[k];
        const float* w = eW1 + (NODE_NF + k) * H_NF;
        #pragma unroll
        for (int j = 0; j < H_NF; ++j) h[j] = fmaf(x, w[j], h[j]);
    }
    float4 at = ((const float4*)edge_attr)[e];
    float av[EDGE_NF] = {at.x, at.y, at.z, at.w};
    #pragma unroll
    for (int k = 0; k < EDGE_NF; ++k) {
        float x = av[k];
        const float* w = eW1 + (2 * NODE_NF + k) * H_NF;
        #pragma unroll
        for (int j = 0; j < H_NF; ++j) h[j] = fmaf(x, w[j], h[j]);
    }
    #pragma unroll
    for (int j = 0; j < H_NF; ++j) h[j] = fmaxf(h[j], 0.f);

    #pragma unroll 1
    for (int j0 = 0; j0 < H_NF; j0 += 8) {
        float acc[8];
        #pragma unroll
        for (int jj = 0; jj < 8; ++jj) acc[jj] = eb2[j0 + jj];
        #pragma unroll
        for (int k = 0; k < H_NF; ++k) {
            float x = h[k];
            #pragma unroll
            for (int jj = 0; jj < 8; ++jj)
                acc[jj] = fmaf(x, W2T[(j0 + jj) * H_NF + k], acc[jj]);
        }
        #pragma unroll
        for (int jj = 0; jj < 8; ++jj)
            atomicAdd(&agg[(size_t)row * H_NF + j0 + jj], fmaxf(acc[jj], 0.f));
    }
}

// ---------------------------------------------------------------------------
// Segment-sum: one 128-thread block per node, sums contiguous ef rows.
// ---------------------------------------------------------------------------
__global__ __launch_bounds__(128)
void agg_kernel(const float* __restrict__ ef,
                const int* __restrict__ starts,
                float* __restrict__ agg)   // [N_NODES][H_NF]
{
    int n = blockIdx.x;
    int j = threadIdx.x;
    int s = starts[n], t = starts[n + 1];
    float acc = 0.f;
    for (int i = s; i < t; ++i) acc += ef[(size_t)i * H_NF + j];
    agg[(size_t)n * H_NF + j] = acc;
}

// ---------------------------------------------------------------------------
// Node MLP layer 1 (node-major agg, in-place nh write).
// ---------------------------------------------------------------------------
__global__ __launch_bounds__(256)
void node_kernel1(const float* __restrict__ node_feats,
                  float* agg_nh,   // in: agg [N][H]; out: n_h [N][H] (aliased)
                  const float* __restrict__ nW1,
                  const float* __restrict__ nb1)
{
    int n = blockIdx.x * 256 + threadIdx.x;
    if (n >= N_NODES) return;
    float acc[H_NF];
    #pragma unroll
    for (int j = 0; j < H_NF; ++j) acc[j] = nb1[j];
    const float* nfp = node_feats + n * NODE_NF;
    #pragma unroll 1
    for (int k = 0; k < NODE_NF; ++k) {
        float x = nfp[k];
        const float* w = nW1 + k * H_NF;
        #pragma unroll
        for (int j = 0; j < H_NF; ++j) acc[j] = fmaf(x, w[j], acc[j]);
    }
    const float4* ap = (const float4*)(agg_nh + (size_t)n * H_NF);
    #pragma unroll 1
    for (int k4 = 0; k4 < H_NF / 4; ++k4) {
        float4 x = ap[k4];
        const float* w0 = nW1 + (NODE_NF + k4 * 4 + 0) * H_NF;
        const float* w1 = nW1 + (NODE_NF + k4 * 4 + 1) * H_NF;
        const float* w2 = nW1 + (NODE_NF + k4 * 4 + 2) * H_NF;
        const float* w3 = nW1 + (NODE_NF + k4 * 4 + 3) * H_NF;
        #pragma unroll
        for (int j = 0; j < H_NF; ++j) {
            acc[j] = fmaf(x.x, w0[j], acc[j]);
            acc[j] = fmaf(x.y, w1[j], acc[j]);
            acc[j] = fmaf(x.z, w2[j], acc[j]);
            acc[j] = fmaf(x.w, w3[j], acc[j]);
        }
    }
    float* op = agg_nh + (size_t)n * H_NF;
    #pragma unroll
    for (int j4 = 0; j4 < H_NF / 4; ++j4) {
        float4 o = make_float4(fmaxf(acc[j4*4+0], 0.f), fmaxf(acc[j4*4+1], 0.f),
                               fmaxf(acc[j4*4+2], 0.f), fmaxf(acc[j4*4+3], 0.f));
        ((float4*)op)[j4] = o;
    }
}

// ---------------------------------------------------------------------------
// Node MLP layer 2 + fused fc_emb head.
// ---------------------------------------------------------------------------
__global__ __launch_bounds__(256)
void node_kernel2(const float* __restrict__ nh,   // [N][H]
                  const float* __restrict__ nW2,
                  const float* __restrict__ nb2,
                  const float* __restrict__ fW,
                  const float* __restrict__ fb,
                  float* __restrict__ out)
{
    int n = blockIdx.x * 256 + threadIdx.x;
    if (n >= N_NODES) return;
    float acc[H_NF];
    #pragma unroll
    for (int j = 0; j < H_NF; ++j) acc[j] = nb2[j];
    const float4* hp = (const float4*)(nh + (size_t)n * H_NF);
    #pragma unroll 1
    for (int k4 = 0; k4 < H_NF / 4; ++k4) {
        float4 x = hp[k4];
        const float* w0 = nW2 + (k4 * 4 + 0) * H_NF;
        const float* w1 = nW2 + (k4 * 4 + 1) * H_NF;
        const float* w2 = nW2 + (k4 * 4 + 2) * H_NF;
        const float* w3 = nW2 + (k4 * 4 + 3) * H_NF;
        #pragma unroll
        for (int j = 0; j < H_NF; ++j) {
            acc[j] = fmaf(x.x, w0[j], acc[j]);
            acc[j] = fmaf(x.y, w1[j], acc[j]);
            acc[j] = fmaf(x.z, w2[j], acc[j]);
            acc[j] = fmaf(x.w, w3[j], acc[j]);
        }
    }
    float o0 = fb[0], o1 = fb[1], o2 = fb[2], o3 = fb[3];
    #pragma unroll
    for (int j = 0; j < H_NF; ++j) {
        o0 = fmaf(acc[j], fW[j * 4 + 0], o0);
        o1 = fmaf(acc[j], fW[j * 4 + 1], o1);
        o2 = fmaf(acc[j], fW[j * 4 + 2], o2);
        o3 = fmaf(acc[j], fW[j * 4 + 3], o3);
    }
    ((float4*)out)[n] = make_float4(o0, o1, o2, o3);
}

extern "C" void kernel_launch(void* const* d_in, const int* in_sizes, int n_in,
                              void* d_out, int out_size, void* d_ws, size_t ws_size,
                              hipStream_t stream)
{
    const float* node_feats = (const float*)d_in[0];
    const int*   edge_index = (const int*)d_in[1];
    const float* edge_attr  = (const float*)d_in[2];
    const float* eW1 = (const float*)d_in[3];
    const float* eb1 = (const float*)d_in[4];
    const float* eW2 = (const float*)d_in[5];
    const float* eb2 = (const float*)d_in[6];
    const float* nW1 = (const float*)d_in[7];
    const float* nb1 = (const float*)d_in[8];
    const float* nW2 = (const float*)d_in[9];
    const float* nb2 = (const float*)d_in[10];
    const float* fW  = (const float*)d_in[11];
    const float* fb  = (const float*)d_in[12];
    float* out = (float*)d_out;

    // ---- workspace carve-up (256B aligned) ----
    size_t off = 0;
    auto carve = [&](size_t bytes) {
        void* p = (char*)d_ws + off;
        off = (off + bytes + 255) & ~(size_t)255;
        return p;
    };
    float* ef     = (float*)carve((size_t)N_EDGES * H_NF * sizeof(float)); // 819.2 MB
    int*   perm   = (int*)  carve((size_t)N_EDGES * sizeof(int));          // 6.4 MB
    int*   hist   = (int*)  carve((size_t)N_NODES * sizeof(int));
    int*   starts = (int*)  carve((size_t)(N_NODES + 1) * sizeof(int));
    int*   cursor = (int*)  carve((size_t)N_NODES * sizeof(int));
    int*   bsum   = (int*)  carve((size_t)(NBLK + 1) * sizeof(int));
    float* agg    = (float*)carve((size_t)N_NODES * H_NF * sizeof(float)); // 51.2 MB
    float* W2T    = (float*)carve((size_t)H_NF * H_NF * sizeof(float));
    size_t required = off;

    transpose_w2<<<(H_NF * H_NF + 255) / 256, 256, 0, stream>>>(eW2, W2T);

    if (ws_size >= required) {
        // sorted / atomic-free path
        hipMemsetAsync(hist, 0, (size_t)N_NODES * sizeof(int), stream);
        hist_kernel<<<(N_EDGES + 255) / 256, 256, 0, stream>>>(edge_index, hist);
        scan1_kernel<<<NBLK, SCAN_B, 0, stream>>>(hist, starts, bsum);
        scan2_kernel<<<1, 64, 0, stream>>>(bsum);
        scan3_kernel<<<(N_NODES + 255) / 256, 256, 0, stream>>>(starts, cursor, bsum);
        permute_kernel<<<(N_EDGES + 255) / 256, 256, 0, stream>>>(edge_index, cursor, perm);
        edge_kernel<<<(N_EDGES + 255) / 256, 256, 0, stream>>>(
            node_feats, edge_index, edge_attr, eW1, eb1, W2T, eb2, perm, ef);
        agg_kernel<<<N_NODES, 128, 0, stream>>>(ef, starts, agg);
    } else {
        // fallback: atomic scatter into node-major agg
        float* agg_fb = (float*)d_ws;
        float* W2T_fb = (float*)((char*)d_ws + (size_t)N_NODES * H_NF * sizeof(float));
        agg = agg_fb;
        transpose_w2<<<(H_NF * H_NF + 255) / 256, 256, 0, stream>>>(eW2, W2T_fb);
        hipMemsetAsync(agg, 0, (size_t)N_NODES * H_NF * sizeof(float), stream);
        edge_kernel_atomic<<<(N_EDGES + 255) / 256, 256, 0, stream>>>(
            node_feats, edge_index, edge_attr, eW1, eb1, W2T_fb, eb2, agg);
    }

    node_kernel1<<<(N_NODES + 255) / 256, 256, 0, stream>>>(node_feats, agg, nW1, nb1);
    node_kernel2<<<(N_NODES + 255) / 256, 256, 0, stream>>>(agg, nW2, nb2, fW, fb, out);
}

// Round 3
// 4603.249 us; speedup vs baseline: 2.3725x; 2.3725x over previous
//
#include <hip/hip_runtime.h>

#define N_NODES 100000
#define N_EDGES 1600000
#define NODE_NF 11
#define EDGE_NF 4
#define H_NF 128
#define EMB_NF 4
#define SCAN_B 1024
#define NBLK ((N_NODES + SCAN_B - 1) / SCAN_B)   // 98

// ---------------------------------------------------------------------------
// Prep: transpose eW2 [k][j] -> W2T [j][k] for contiguous scalar weight rows.
// ---------------------------------------------------------------------------
__global__ __launch_bounds__(256)
void transpose_w2(const float* __restrict__ W, float* __restrict__ WT) {
    int i = blockIdx.x * 256 + threadIdx.x;
    if (i < H_NF * H_NF) {
        int k = i >> 7;
        int j = i & (H_NF - 1);
        WT[j * H_NF + k] = W[i];
    }
}

// ---------------------------------------------------------------------------
// Counting sort of edges by row (target node). hist -> scan -> permute.
// ---------------------------------------------------------------------------
__global__ __launch_bounds__(256)
void hist_kernel(const int* __restrict__ edge_index, int* hist) {
    int e = blockIdx.x * 256 + threadIdx.x;
    if (e < N_EDGES) atomicAdd(&hist[edge_index[e]], 1);
}

__global__ __launch_bounds__(SCAN_B)
void scan1_kernel(const int* __restrict__ hist, int* starts, int* bsum) {
    __shared__ int buf[SCAN_B];
    int i = blockIdx.x * SCAN_B + threadIdx.x;
    int v = (i < N_NODES) ? hist[i] : 0;
    buf[threadIdx.x] = v;
    __syncthreads();
    for (int off = 1; off < SCAN_B; off <<= 1) {
        int t = (threadIdx.x >= off) ? buf[threadIdx.x - off] : 0;
        __syncthreads();
        buf[threadIdx.x] += t;
        __syncthreads();
    }
    if (i < N_NODES) starts[i] = buf[threadIdx.x] - v;   // local exclusive
    if (threadIdx.x == SCAN_B - 1) bsum[blockIdx.x] = buf[SCAN_B - 1];
}

__global__ void scan2_kernel(int* bsum) {
    if (threadIdx.x == 0 && blockIdx.x == 0) {
        int run = 0;
        for (int b = 0; b < NBLK; ++b) { int t = bsum[b]; bsum[b] = run; run += t; }
        bsum[NBLK] = run;
    }
}

__global__ __launch_bounds__(256)
void scan3_kernel(int* starts, int* cursor, const int* __restrict__ bsum) {
    int i = blockIdx.x * 256 + threadIdx.x;
    if (i < N_NODES) {
        int s = starts[i] + bsum[i / SCAN_B];
        starts[i] = s;
        cursor[i] = s;
    }
    if (i == 0) starts[N_NODES] = bsum[NBLK];
}

__global__ __launch_bounds__(256)
void permute_kernel(const int* __restrict__ edge_index, int* cursor, int* perm) {
    int e = blockIdx.x * 256 + threadIdx.x;
    if (e < N_EDGES) {
        int pos = atomicAdd(&cursor[edge_index[e]], 1);
        perm[pos] = e;
    }
}

// ---------------------------------------------------------------------------
// Fused edge MLP + segmented wave reduction + sparse atomic flush.
// Slot i (sorted by row) -> edge perm[i]. Within a wave, equal rows form
// contiguous runs; a segmented inclusive scan (6 shfl_up steps) sums each
// run, and only the run-tail lane issues the atomicAdd. ~16M atomics total
// instead of 204.8M, with sorted (cache-friendly) targets.
// N_EDGES % 256 == 0 -> no bounds check.
// ---------------------------------------------------------------------------
__global__ __launch_bounds__(256)
void edge_agg_kernel(const float* __restrict__ node_feats,
                     const int*   __restrict__ edge_index,
                     const float* __restrict__ edge_attr,
                     const float* __restrict__ eW1,
                     const float* __restrict__ eb1,
                     const float* __restrict__ W2T,
                     const float* __restrict__ eb2,
                     const int*   __restrict__ perm,
                     float* agg)   // [N_NODES][H_NF]
{
    int i = blockIdx.x * 256 + threadIdx.x;
    int lane = threadIdx.x & 63;
    int e = perm[i];
    int row = edge_index[e];
    int col = edge_index[N_EDGES + e];

    // --- segment topology within the wave (row runs are contiguous) ---
    int row_prev = __shfl_up(row, 1);
    bool is_head = (lane == 0) || (row_prev != row);
    unsigned long long heads = __ballot(is_head);
    unsigned long long below = heads & (~0ull >> (63 - lane));
    int head = 63 - __builtin_clzll(below);
    int row_next = __shfl_down(row, 1);
    bool is_tail = (lane == 63) || (row_next != row);
    int dist = lane - head;
    bool t1  = dist >= 1,  t2  = dist >= 2,  t4  = dist >= 4;
    bool t8  = dist >= 8,  t16 = dist >= 16, t32 = dist >= 32;

    // --- edge MLP layer 1: 26 -> 128, h in VGPRs ---
    float h[H_NF];
    #pragma unroll
    for (int j = 0; j < H_NF; ++j) h[j] = eb1[j];

    const float* srcp = node_feats + row * NODE_NF;
    #pragma unroll 1
    for (int k = 0; k < NODE_NF; ++k) {
        float x = srcp[k];
        const float* w = eW1 + k * H_NF;
        #pragma unroll
        for (int j = 0; j < H_NF; ++j) h[j] = fmaf(x, w[j], h[j]);
    }
    const float* dstp = node_feats + col * NODE_NF;
    #pragma unroll 1
    for (int k = 0; k < NODE_NF; ++k) {
        float x = dstp[k];
        const float* w = eW1 + (NODE_NF + k) * H_NF;
        #pragma unroll
        for (int j = 0; j < H_NF; ++j) h[j] = fmaf(x, w[j], h[j]);
    }
    float4 at = ((const float4*)edge_attr)[e];
    float av[EDGE_NF] = {at.x, at.y, at.z, at.w};
    #pragma unroll
    for (int k = 0; k < EDGE_NF; ++k) {
        float x = av[k];
        const float* w = eW1 + (2 * NODE_NF + k) * H_NF;
        #pragma unroll
        for (int j = 0; j < H_NF; ++j) h[j] = fmaf(x, w[j], h[j]);
    }
    #pragma unroll
    for (int j = 0; j < H_NF; ++j) h[j] = fmaxf(h[j], 0.f);

    // --- layer 2 (128 -> 128) in 8-feature tiles + segmented scan + flush ---
    #pragma unroll 1
    for (int j0 = 0; j0 < H_NF; j0 += 8) {
        float acc[8];
        #pragma unroll
        for (int jj = 0; jj < 8; ++jj) acc[jj] = eb2[j0 + jj];
        #pragma unroll
        for (int k = 0; k < H_NF; ++k) {
            float x = h[k];
            #pragma unroll
            for (int jj = 0; jj < 8; ++jj)
                acc[jj] = fmaf(x, W2T[(j0 + jj) * H_NF + k], acc[jj]);
        }
        #pragma unroll
        for (int jj = 0; jj < 8; ++jj) {
            float v = fmaxf(acc[jj], 0.f);
            float o;
            o = __shfl_up(v, 1);  v += t1  ? o : 0.f;
            o = __shfl_up(v, 2);  v += t2  ? o : 0.f;
            o = __shfl_up(v, 4);  v += t4  ? o : 0.f;
            o = __shfl_up(v, 8);  v += t8  ? o : 0.f;
            o = __shfl_up(v, 16); v += t16 ? o : 0.f;
            o = __shfl_up(v, 32); v += t32 ? o : 0.f;
            if (is_tail)
                unsafeAtomicAdd(&agg[(size_t)row * H_NF + j0 + jj], v);
        }
    }
}

// ---------------------------------------------------------------------------
// Fallback (ws too small for sort scratch): atomic scatter, node-major agg.
// ---------------------------------------------------------------------------
__global__ __launch_bounds__(256)
void edge_kernel_atomic(const float* __restrict__ node_feats,
                        const int*   __restrict__ edge_index,
                        const float* __restrict__ edge_attr,
                        const float* __restrict__ eW1,
                        const float* __restrict__ eb1,
                        const float* __restrict__ W2T,
                        const float* __restrict__ eb2,
                        float* agg)   // [N_NODES][H_NF]
{
    int e = blockIdx.x * 256 + threadIdx.x;
    if (e >= N_EDGES) return;
    int row = edge_index[e];
    int col = edge_index[N_EDGES + e];

    float h[H_NF];
    #pragma unroll
    for (int j = 0; j < H_NF; ++j) h[j] = eb1[j];
    const float* srcp = node_feats + row * NODE_NF;
    #pragma unroll 1
    for (int k = 0; k < NODE_NF; ++k) {
        float x = srcp[k];
        const float* w = eW1 + k * H_NF;
        #pragma unroll
        for (int j = 0; j < H_NF; ++j) h[j] = fmaf(x, w[j], h[j]);
    }
    const float* dstp = node_feats + col * NODE_NF;
    #pragma unroll 1
    for (int k = 0; k < NODE_NF; ++k) {
        float x = dstp[k];
        const float* w = eW1 + (NODE_NF + k) * H_NF;
        #pragma unroll
        for (int j = 0; j < H_NF; ++j) h[j] = fmaf(x, w[j], h[j]);
    }
    float4 at = ((const float4*)edge_attr)[e];
    float av[EDGE_NF] = {at.x, at.y, at.z, at.w};
    #pragma unroll
    for (int k = 0; k < EDGE_NF; ++k) {
        float x = av[k];
        const float* w = eW1 + (2 * NODE_NF + k) * H_NF;
        #pragma unroll
        for (int j = 0; j < H_NF; ++j) h[j] = fmaf(x, w[j], h[j]);
    }
    #pragma unroll
    for (int j = 0; j < H_NF; ++j) h[j] = fmaxf(h[j], 0.f);

    #pragma unroll 1
    for (int j0 = 0; j0 < H_NF; j0 += 8) {
        float acc[8];
        #pragma unroll
        for (int jj = 0; jj < 8; ++jj) acc[jj] = eb2[j0 + jj];
        #pragma unroll
        for (int k = 0; k < H_NF; ++k) {
            float x = h[k];
            #pragma unroll
            for (int jj = 0; jj < 8; ++jj)
                acc[jj] = fmaf(x, W2T[(j0 + jj) * H_NF + k], acc[jj]);
        }
        #pragma unroll
        for (int jj = 0; jj < 8; ++jj)
            unsafeAtomicAdd(&agg[(size_t)row * H_NF + j0 + jj], fmaxf(acc[jj], 0.f));
    }
}

// ---------------------------------------------------------------------------
// Node MLP layer 1 (node-major agg, in-place nh write).
// ---------------------------------------------------------------------------
__global__ __launch_bounds__(256)
void node_kernel1(const float* __restrict__ node_feats,
                  float* agg_nh,   // in: agg [N][H]; out: n_h [N][H] (aliased)
                  const float* __restrict__ nW1,
                  const float* __restrict__ nb1)
{
    int n = blockIdx.x * 256 + threadIdx.x;
    if (n >= N_NODES) return;
    float acc[H_NF];
    #pragma unroll
    for (int j = 0; j < H_NF; ++j) acc[j] = nb1[j];
    const float* nfp = node_feats + n * NODE_NF;
    #pragma unroll 1
    for (int k = 0; k < NODE_NF; ++k) {
        float x = nfp[k];
        const float* w = nW1 + k * H_NF;
        #pragma unroll
        for (int j = 0; j < H_NF; ++j) acc[j] = fmaf(x, w[j], acc[j]);
    }
    const float4* ap = (const float4*)(agg_nh + (size_t)n * H_NF);
    #pragma unroll 1
    for (int k4 = 0; k4 < H_NF / 4; ++k4) {
        float4 x = ap[k4];
        const float* w0 = nW1 + (NODE_NF + k4 * 4 + 0) * H_NF;
        const float* w1 = nW1 + (NODE_NF + k4 * 4 + 1) * H_NF;
        const float* w2 = nW1 + (NODE_NF + k4 * 4 + 2) * H_NF;
        const float* w3 = nW1 + (NODE_NF + k4 * 4 + 3) * H_NF;
        #pragma unroll
        for (int j = 0; j < H_NF; ++j) {
            acc[j] = fmaf(x.x, w0[j], acc[j]);
            acc[j] = fmaf(x.y, w1[j], acc[j]);
            acc[j] = fmaf(x.z, w2[j], acc[j]);
            acc[j] = fmaf(x.w, w3[j], acc[j]);
        }
    }
    float* op = agg_nh + (size_t)n * H_NF;
    #pragma unroll
    for (int j4 = 0; j4 < H_NF / 4; ++j4) {
        float4 o = make_float4(fmaxf(acc[j4*4+0], 0.f), fmaxf(acc[j4*4+1], 0.f),
                               fmaxf(acc[j4*4+2], 0.f), fmaxf(acc[j4*4+3], 0.f));
        ((float4*)op)[j4] = o;
    }
}

// ---------------------------------------------------------------------------
// Node MLP layer 2 + fused fc_emb head.
// ---------------------------------------------------------------------------
__global__ __launch_bounds__(256)
void node_kernel2(const float* __restrict__ nh,   // [N][H]
                  const float* __restrict__ nW2,
                  const float* __restrict__ nb2,
                  const float* __restrict__ fW,
                  const float* __restrict__ fb,
                  float* __restrict__ out)
{
    int n = blockIdx.x * 256 + threadIdx.x;
    if (n >= N_NODES) return;
    float acc[H_NF];
    #pragma unroll
    for (int j = 0; j < H_NF; ++j) acc[j] = nb2[j];
    const float4* hp = (const float4*)(nh + (size_t)n * H_NF);
    #pragma unroll 1
    for (int k4 = 0; k4 < H_NF / 4; ++k4) {
        float4 x = hp[k4];
        const float* w0 = nW2 + (k4 * 4 + 0) * H_NF;
        const float* w1 = nW2 + (k4 * 4 + 1) * H_NF;
        const float* w2 = nW2 + (k4 * 4 + 2) * H_NF;
        const float* w3 = nW2 + (k4 * 4 + 3) * H_NF;
        #pragma unroll
        for (int j = 0; j < H_NF; ++j) {
            acc[j] = fmaf(x.x, w0[j], acc[j]);
            acc[j] = fmaf(x.y, w1[j], acc[j]);
            acc[j] = fmaf(x.z, w2[j], acc[j]);
            acc[j] = fmaf(x.w, w3[j], acc[j]);
        }
    }
    float o0 = fb[0], o1 = fb[1], o2 = fb[2], o3 = fb[3];
    #pragma unroll
    for (int j = 0; j < H_NF; ++j) {
        o0 = fmaf(acc[j], fW[j * 4 + 0], o0);
        o1 = fmaf(acc[j], fW[j * 4 + 1], o1);
        o2 = fmaf(acc[j], fW[j * 4 + 2], o2);
        o3 = fmaf(acc[j], fW[j * 4 + 3], o3);
    }
    ((float4*)out)[n] = make_float4(o0, o1, o2, o3);
}

extern "C" void kernel_launch(void* const* d_in, const int* in_sizes, int n_in,
                              void* d_out, int out_size, void* d_ws, size_t ws_size,
                              hipStream_t stream)
{
    const float* node_feats = (const float*)d_in[0];
    const int*   edge_index = (const int*)d_in[1];
    const float* edge_attr  = (const float*)d_in[2];
    const float* eW1 = (const float*)d_in[3];
    const float* eb1 = (const float*)d_in[4];
    const float* eW2 = (const float*)d_in[5];
    const float* eb2 = (const float*)d_in[6];
    const float* nW1 = (const float*)d_in[7];
    const float* nb1 = (const float*)d_in[8];
    const float* nW2 = (const float*)d_in[9];
    const float* nb2 = (const float*)d_in[10];
    const float* fW  = (const float*)d_in[11];
    const float* fb  = (const float*)d_in[12];
    float* out = (float*)d_out;

    // ---- workspace carve-up (256B aligned): ~59 MB ----
    size_t off = 0;
    auto carve = [&](size_t bytes) {
        void* p = (char*)d_ws + off;
        off = (off + bytes + 255) & ~(size_t)255;
        return p;
    };
    float* agg    = (float*)carve((size_t)N_NODES * H_NF * sizeof(float)); // 51.2 MB
    int*   perm   = (int*)  carve((size_t)N_EDGES * sizeof(int));          // 6.4 MB
    int*   hist   = (int*)  carve((size_t)N_NODES * sizeof(int));
    int*   starts = (int*)  carve((size_t)(N_NODES + 1) * sizeof(int));
    int*   cursor = (int*)  carve((size_t)N_NODES * sizeof(int));
    int*   bsum   = (int*)  carve((size_t)(NBLK + 1) * sizeof(int));
    float* W2T    = (float*)carve((size_t)H_NF * H_NF * sizeof(float));
    size_t required = off;

    if (ws_size >= required) {
        transpose_w2<<<(H_NF * H_NF + 255) / 256, 256, 0, stream>>>(eW2, W2T);
        hipMemsetAsync(agg, 0, (size_t)N_NODES * H_NF * sizeof(float), stream);
        hipMemsetAsync(hist, 0, (size_t)N_NODES * sizeof(int), stream);
        hist_kernel<<<(N_EDGES + 255) / 256, 256, 0, stream>>>(edge_index, hist);
        scan1_kernel<<<NBLK, SCAN_B, 0, stream>>>(hist, starts, bsum);
        scan2_kernel<<<1, 64, 0, stream>>>(bsum);
        scan3_kernel<<<(N_NODES + 255) / 256, 256, 0, stream>>>(starts, cursor, bsum);
        permute_kernel<<<(N_EDGES + 255) / 256, 256, 0, stream>>>(edge_index, cursor, perm);
        edge_agg_kernel<<<N_EDGES / 256, 256, 0, stream>>>(
            node_feats, edge_index, edge_attr, eW1, eb1, W2T, eb2, perm, agg);
    } else {
        // fallback: atomic scatter into node-major agg (needs 51.3 MB)
        agg = (float*)d_ws;
        float* W2T_fb = (float*)((char*)d_ws + (size_t)N_NODES * H_NF * sizeof(float));
        transpose_w2<<<(H_NF * H_NF + 255) / 256, 256, 0, stream>>>(eW2, W2T_fb);
        hipMemsetAsync(agg, 0, (size_t)N_NODES * H_NF * sizeof(float), stream);
        edge_kernel_atomic<<<(N_EDGES + 255) / 256, 256, 0, stream>>>(
            node_feats, edge_index, edge_attr, eW1, eb1, W2T_fb, eb2, agg);
    }

    node_kernel1<<<(N_NODES + 255) / 256, 256, 0, stream>>>(node_feats, agg, nW1, nb1);
    node_kernel2<<<(N_NODES + 255) / 256, 256, 0, stream>>>(agg, nW2, nb2, fW, fb, out);
}

// Round 4
// 956.671 us; speedup vs baseline: 11.4160x; 4.8117x over previous
//
#include <hip/hip_runtime.h>

#define N_NODES 100000
#define N_EDGES 1600000
#define NODE_NF 11
#define EDGE_NF 4
#define H_NF 128
#define EMB_NF 4
#define SCAN_B 1024
#define NBLK ((N_NODES + SCAN_B - 1) / SCAN_B)   // 98

// fp16 padded strides (units: fp16 elements). 40*2=80B, 136*2=272B — both
// 16B-aligned row starts for ds_read_b128, non-pow2 dword count for bank spread.
#define K1P 40    // layer-1 K pad: 26 used, zeros to 40
#define K2P 136   // layer-2 K pad: 128 used, zeros to 136

typedef _Float16 half8 __attribute__((ext_vector_type(8)));
typedef float floatx4 __attribute__((ext_vector_type(4)));

// ---------------------------------------------------------------------------
// Prep: cast weights to fp16, n-major, K-padded.
// w1h[n][k] = k<26 ? eW1[k][n] : 0      (128 x 40)
// w2h[n][k] = k<128 ? eW2[k][n] : 0     (128 x 136)
// ---------------------------------------------------------------------------
__global__ __launch_bounds__(256)
void prep_w1h(const float* __restrict__ eW1, _Float16* __restrict__ w1h) {
    int i = blockIdx.x * 256 + threadIdx.x;
    if (i < H_NF * K1P) {
        int n = i / K1P, k = i % K1P;
        w1h[i] = (k < 2 * NODE_NF + EDGE_NF) ? (_Float16)eW1[k * H_NF + n] : (_Float16)0.f;
    }
}
__global__ __launch_bounds__(256)
void prep_w2h(const float* __restrict__ eW2, _Float16* __restrict__ w2h) {
    int i = blockIdx.x * 256 + threadIdx.x;
    if (i < H_NF * K2P) {
        int n = i / K2P, k = i % K2P;
        w2h[i] = (k < H_NF) ? (_Float16)eW2[k * H_NF + n] : (_Float16)0.f;
    }
}

// ---------------------------------------------------------------------------
// Prep (fallback path only): transpose eW2 fp32.
// ---------------------------------------------------------------------------
__global__ __launch_bounds__(256)
void transpose_w2(const float* __restrict__ W, float* __restrict__ WT) {
    int i = blockIdx.x * 256 + threadIdx.x;
    if (i < H_NF * H_NF) {
        int k = i >> 7;
        int j = i & (H_NF - 1);
        WT[j * H_NF + k] = W[i];
    }
}

// ---------------------------------------------------------------------------
// Counting sort of edges by row (target node). hist -> scan -> permute.
// ---------------------------------------------------------------------------
__global__ __launch_bounds__(256)
void hist_kernel(const int* __restrict__ edge_index, int* hist) {
    int e = blockIdx.x * 256 + threadIdx.x;
    if (e < N_EDGES) atomicAdd(&hist[edge_index[e]], 1);
}

__global__ __launch_bounds__(SCAN_B)
void scan1_kernel(const int* __restrict__ hist, int* starts, int* bsum) {
    __shared__ int buf[SCAN_B];
    int i = blockIdx.x * SCAN_B + threadIdx.x;
    int v = (i < N_NODES) ? hist[i] : 0;
    buf[threadIdx.x] = v;
    __syncthreads();
    for (int off = 1; off < SCAN_B; off <<= 1) {
        int t = (threadIdx.x >= off) ? buf[threadIdx.x - off] : 0;
        __syncthreads();
        buf[threadIdx.x] += t;
        __syncthreads();
    }
    if (i < N_NODES) starts[i] = buf[threadIdx.x] - v;
    if (threadIdx.x == SCAN_B - 1) bsum[blockIdx.x] = buf[SCAN_B - 1];
}

__global__ void scan2_kernel(int* bsum) {
    if (threadIdx.x == 0 && blockIdx.x == 0) {
        int run = 0;
        for (int b = 0; b < NBLK; ++b) { int t = bsum[b]; bsum[b] = run; run += t; }
        bsum[NBLK] = run;
    }
}

__global__ __launch_bounds__(256)
void scan3_kernel(int* starts, int* cursor, const int* __restrict__ bsum) {
    int i = blockIdx.x * 256 + threadIdx.x;
    if (i < N_NODES) {
        int s = starts[i] + bsum[i / SCAN_B];
        starts[i] = s;
        cursor[i] = s;
    }
    if (i == 0) starts[N_NODES] = bsum[NBLK];
}

__global__ __launch_bounds__(256)
void permute_kernel(const int* __restrict__ edge_index, int* cursor, int* perm) {
    int e = blockIdx.x * 256 + threadIdx.x;
    if (e < N_EDGES) {
        int pos = atomicAdd(&cursor[edge_index[e]], 1);
        perm[pos] = e;
    }
}

// ---------------------------------------------------------------------------
// MFMA edge MLP + LDS segmented reduction.
// Block = 256 thr = 4 waves, 64 sorted slots. Wave w owns edges [w*16,w*16+16).
// Layer1: 8x mfma_f32_16x16x32_f16 (K=32 covers padded 26).
// Layer2: 8 n-tiles x 4 k-steps = 32 mfma.
// ef tile [64][128] f32 overlays Ain/W1/h LDS (exactly 32KB), then a
// feature-parallel segmented scan flushes runs with contiguous atomics.
// Fragment layouts (verified m89/m91/m118/m120):
//   A: lane holds A[m=lane&15][k=quad*8+j]   (8 consecutive k -> b128)
//   B: lane holds B[k=quad*8+j][n=lane&15]   (weights stored n-major)
//   C/D: D[row=quad*4+reg][col=lane&15]
// ---------------------------------------------------------------------------
#define LDS_AIN   0                         // 64*40*2  = 5120 B
#define LDS_W1    5120                      // 128*40*2 = 10240 B
#define LDS_H     15360                     // 64*136*2 = 17408 B
#define LDS_W2    32768                     // 128*136*2= 34816 B
#define LDS_ROWS  67584                     // 64*4     = 256 B
#define LDS_TOTAL 67840

__global__ __launch_bounds__(256)
void edge_mfma_kernel(const float* __restrict__ node_feats,
                      const int*   __restrict__ edge_index,
                      const float* __restrict__ edge_attr,
                      const _Float16* __restrict__ w1h,   // [128][40]
                      const float* __restrict__ eb1,
                      const _Float16* __restrict__ w2h,   // [128][136]
                      const float* __restrict__ eb2,
                      const int*   __restrict__ perm,
                      float* agg)   // [N_NODES][H_NF]
{
    __shared__ __align__(16) char smem[LDS_TOTAL];
    _Float16* Ain  = (_Float16*)(smem + LDS_AIN);
    _Float16* W1s  = (_Float16*)(smem + LDS_W1);
    _Float16* Hs   = (_Float16*)(smem + LDS_H);
    _Float16* W2s  = (_Float16*)(smem + LDS_W2);
    float*    efS  = (float*)(smem + LDS_AIN);   // aliases Ain+W1+H (32768 B)
    int*      rowsS = (int*)(smem + LDS_ROWS);

    int t = threadIdx.x;

    // ---- stage weights global -> LDS (vector b128 copies) ----
    {
        const float4* g1 = (const float4*)w1h;   // 10240/16 = 640
        float4* s1 = (float4*)W1s;
        for (int i = t; i < 640; i += 256) s1[i] = g1[i];
        const float4* g2 = (const float4*)w2h;   // 34816/16 = 2176
        float4* s2 = (float4*)W2s;
        for (int i = t; i < 2176; i += 256) s2[i] = g2[i];
    }

    // ---- gather 64 edges' inputs -> Ain [64][K1P] fp16 ----
    if (t < 128) {
        int el = t & 63;
        int slot = blockIdx.x * 64 + el;
        int e = perm[slot];
        _Float16* arow = Ain + el * K1P;
        if (t < 64) {
            int row = edge_index[e];
            rowsS[el] = row;
            const float* p = node_feats + (size_t)row * NODE_NF;
            #pragma unroll
            for (int k = 0; k < NODE_NF; ++k) arow[k] = (_Float16)p[k];
            #pragma unroll
            for (int k = 2 * NODE_NF + EDGE_NF; k < K1P; ++k) arow[k] = (_Float16)0.f;
        } else {
            int col = edge_index[N_EDGES + e];
            const float* p = node_feats + (size_t)col * NODE_NF;
            #pragma unroll
            for (int k = 0; k < NODE_NF; ++k) arow[NODE_NF + k] = (_Float16)p[k];
            float4 a4 = ((const float4*)edge_attr)[e];
            arow[22] = (_Float16)a4.x; arow[23] = (_Float16)a4.y;
            arow[24] = (_Float16)a4.z; arow[25] = (_Float16)a4.w;
        }
    }
    __syncthreads();

    int w = t >> 6, lane = t & 63;
    int m = lane & 15, quad = lane >> 4;

    // ---- layer 1: 26(pad32) -> 128 ----
    half8 a1 = *(const half8*)(Ain + (w * 16 + m) * K1P + quad * 8);
    #pragma unroll
    for (int tile = 0; tile < 8; ++tile) {
        half8 b = *(const half8*)(W1s + (tile * 16 + m) * K1P + quad * 8);
        floatx4 c = {0.f, 0.f, 0.f, 0.f};
        c = __builtin_amdgcn_mfma_f32_16x16x32_f16(a1, b, c, 0, 0, 0);
        int n = tile * 16 + m;
        float bv = eb1[n];
        #pragma unroll
        for (int r = 0; r < 4; ++r) {
            float v = fmaxf(c[r] + bv, 0.f);
            Hs[(w * 16 + quad * 4 + r) * K2P + n] = (_Float16)v;
        }
    }
    // same-wave h write->read: lgkmcnt ordering suffices, no barrier.

    // ---- layer 2: 128 -> 128 ----
    half8 a2[4];
    #pragma unroll
    for (int ks = 0; ks < 4; ++ks)
        a2[ks] = *(const half8*)(Hs + (w * 16 + m) * K2P + ks * 32 + quad * 8);

    float vals[32];
    #pragma unroll
    for (int tile = 0; tile < 8; ++tile) {
        floatx4 c = {0.f, 0.f, 0.f, 0.f};
        #pragma unroll
        for (int ks = 0; ks < 4; ++ks) {
            half8 b = *(const half8*)(W2s + (tile * 16 + m) * K2P + ks * 32 + quad * 8);
            c = __builtin_amdgcn_mfma_f32_16x16x32_f16(a2[ks], b, c, 0, 0, 0);
        }
        float bv = eb2[tile * 16 + m];
        #pragma unroll
        for (int r = 0; r < 4; ++r)
            vals[tile * 4 + r] = fmaxf(c[r] + bv, 0.f);
    }

    __syncthreads();   // all waves done reading Ain/W1/Hs before ef overlay

    #pragma unroll
    for (int tile = 0; tile < 8; ++tile)
        #pragma unroll
        for (int r = 0; r < 4; ++r)
            efS[(w * 16 + quad * 4 + r) * H_NF + tile * 16 + m] = vals[tile * 4 + r];

    __syncthreads();

    // ---- segmented reduction: thread = (feature f, edge-group g of 32) ----
    {
        int f = t & 127, g = t >> 7;
        int base = g * 32;
        int cur = rowsS[base];
        float acc = efS[base * H_NF + f];
        #pragma unroll 1
        for (int i = 1; i < 32; ++i) {
            int r = rowsS[base + i];             // wave-uniform
            float v = efS[(base + i) * H_NF + f];
            if (r != cur) {                       // wave-uniform branch
                unsafeAtomicAdd(&agg[(size_t)cur * H_NF + f], acc);
                acc = v; cur = r;
            } else {
                acc += v;
            }
        }
        unsafeAtomicAdd(&agg[(size_t)cur * H_NF + f], acc);
    }
}

// ---------------------------------------------------------------------------
// Fallback (ws too small for sort scratch): fp32 atomic scatter.
// ---------------------------------------------------------------------------
__global__ __launch_bounds__(256)
void edge_kernel_atomic(const float* __restrict__ node_feats,
                        const int*   __restrict__ edge_index,
                        const float* __restrict__ edge_attr,
                        const float* __restrict__ eW1,
                        const float* __restrict__ eb1,
                        const float* __restrict__ W2T,
                        const float* __restrict__ eb2,
                        float* agg)   // [N_NODES][H_NF]
{
    int e = blockIdx.x * 256 + threadIdx.x;
    if (e >= N_EDGES) return;
    int row = edge_index[e];
    int col = edge_index[N_EDGES + e];

    float h[H_NF];
    #pragma unroll
    for (int j = 0; j < H_NF; ++j) h[j] = eb1[j];
    const float* srcp = node_feats + row * NODE_NF;
    #pragma unroll 1
    for (int k = 0; k < NODE_NF; ++k) {
        float x = srcp[k];
        const float* w = eW1 + k * H_NF;
        #pragma unroll
        for (int j = 0; j < H_NF; ++j) h[j] = fmaf(x, w[j], h[j]);
    }
    const float* dstp = node_feats + col * NODE_NF;
    #pragma unroll 1
    for (int k = 0; k < NODE_NF; ++k) {
        float x = dstp[k];
        const float* w = eW1 + (NODE_NF + k) * H_NF;
        #pragma unroll
        for (int j = 0; j < H_NF; ++j) h[j] = fmaf(x, w[j], h[j]);
    }
    float4 at = ((const float4*)edge_attr)[e];
    float av[EDGE_NF] = {at.x, at.y, at.z, at.w};
    #pragma unroll
    for (int k = 0; k < EDGE_NF; ++k) {
        float x = av[k];
        const float* w = eW1 + (2 * NODE_NF + k) * H_NF;
        #pragma unroll
        for (int j = 0; j < H_NF; ++j) h[j] = fmaf(x, w[j], h[j]);
    }
    #pragma unroll
    for (int j = 0; j < H_NF; ++j) h[j] = fmaxf(h[j], 0.f);

    #pragma unroll 1
    for (int j0 = 0; j0 < H_NF; j0 += 8) {
        float acc[8];
        #pragma unroll
        for (int jj = 0; jj < 8; ++jj) acc[jj] = eb2[j0 + jj];
        #pragma unroll
        for (int k = 0; k < H_NF; ++k) {
            float x = h[k];
            #pragma unroll
            for (int jj = 0; jj < 8; ++jj)
                acc[jj] = fmaf(x, W2T[(j0 + jj) * H_NF + k], acc[jj]);
        }
        #pragma unroll
        for (int jj = 0; jj < 8; ++jj)
            unsafeAtomicAdd(&agg[(size_t)row * H_NF + j0 + jj], fmaxf(acc[jj], 0.f));
    }
}

// ---------------------------------------------------------------------------
// Node MLP layer 1 (node-major agg, in-place nh write).
// ---------------------------------------------------------------------------
__global__ __launch_bounds__(256)
void node_kernel1(const float* __restrict__ node_feats,
                  float* agg_nh,
                  const float* __restrict__ nW1,
                  const float* __restrict__ nb1)
{
    int n = blockIdx.x * 256 + threadIdx.x;
    if (n >= N_NODES) return;
    float acc[H_NF];
    #pragma unroll
    for (int j = 0; j < H_NF; ++j) acc[j] = nb1[j];
    const float* nfp = node_feats + n * NODE_NF;
    #pragma unroll 1
    for (int k = 0; k < NODE_NF; ++k) {
        float x = nfp[k];
        const float* w = nW1 + k * H_NF;
        #pragma unroll
        for (int j = 0; j < H_NF; ++j) acc[j] = fmaf(x, w[j], acc[j]);
    }
    const float4* ap = (const float4*)(agg_nh + (size_t)n * H_NF);
    #pragma unroll 1
    for (int k4 = 0; k4 < H_NF / 4; ++k4) {
        float4 x = ap[k4];
        const float* w0 = nW1 + (NODE_NF + k4 * 4 + 0) * H_NF;
        const float* w1 = nW1 + (NODE_NF + k4 * 4 + 1) * H_NF;
        const float* w2 = nW1 + (NODE_NF + k4 * 4 + 2) * H_NF;
        const float* w3 = nW1 + (NODE_NF + k4 * 4 + 3) * H_NF;
        #pragma unroll
        for (int j = 0; j < H_NF; ++j) {
            acc[j] = fmaf(x.x, w0[j], acc[j]);
            acc[j] = fmaf(x.y, w1[j], acc[j]);
            acc[j] = fmaf(x.z, w2[j], acc[j]);
            acc[j] = fmaf(x.w, w3[j], acc[j]);
        }
    }
    float* op = agg_nh + (size_t)n * H_NF;
    #pragma unroll
    for (int j4 = 0; j4 < H_NF / 4; ++j4) {
        float4 o = make_float4(fmaxf(acc[j4*4+0], 0.f), fmaxf(acc[j4*4+1], 0.f),
                               fmaxf(acc[j4*4+2], 0.f), fmaxf(acc[j4*4+3], 0.f));
        ((float4*)op)[j4] = o;
    }
}

// ---------------------------------------------------------------------------
// Node MLP layer 2 + fused fc_emb head.
// ---------------------------------------------------------------------------
__global__ __launch_bounds__(256)
void node_kernel2(const float* __restrict__ nh,
                  const float* __restrict__ nW2,
                  const float* __restrict__ nb2,
                  const float* __restrict__ fW,
                  const float* __restrict__ fb,
                  float* __restrict__ out)
{
    int n = blockIdx.x * 256 + threadIdx.x;
    if (n >= N_NODES) return;
    float acc[H_NF];
    #pragma unroll
    for (int j = 0; j < H_NF; ++j) acc[j] = nb2[j];
    const float4* hp = (const float4*)(nh + (size_t)n * H_NF);
    #pragma unroll 1
    for (int k4 = 0; k4 < H_NF / 4; ++k4) {
        float4 x = hp[k4];
        const float* w0 = nW2 + (k4 * 4 + 0) * H_NF;
        const float* w1 = nW2 + (k4 * 4 + 1) * H_NF;
        const float* w2 = nW2 + (k4 * 4 + 2) * H_NF;
        const float* w3 = nW2 + (k4 * 4 + 3) * H_NF;
        #pragma unroll
        for (int j = 0; j < H_NF; ++j) {
            acc[j] = fmaf(x.x, w0[j], acc[j]);
            acc[j] = fmaf(x.y, w1[j], acc[j]);
            acc[j] = fmaf(x.z, w2[j], acc[j]);
            acc[j] = fmaf(x.w, w3[j], acc[j]);
        }
    }
    float o0 = fb[0], o1 = fb[1], o2 = fb[2], o3 = fb[3];
    #pragma unroll
    for (int j = 0; j < H_NF; ++j) {
        o0 = fmaf(acc[j], fW[j * 4 + 0], o0);
        o1 = fmaf(acc[j], fW[j * 4 + 1], o1);
        o2 = fmaf(acc[j], fW[j * 4 + 2], o2);
        o3 = fmaf(acc[j], fW[j * 4 + 3], o3);
    }
    ((float4*)out)[n] = make_float4(o0, o1, o2, o3);
}

extern "C" void kernel_launch(void* const* d_in, const int* in_sizes, int n_in,
                              void* d_out, int out_size, void* d_ws, size_t ws_size,
                              hipStream_t stream)
{
    const float* node_feats = (const float*)d_in[0];
    const int*   edge_index = (const int*)d_in[1];
    const float* edge_attr  = (const float*)d_in[2];
    const float* eW1 = (const float*)d_in[3];
    const float* eb1 = (const float*)d_in[4];
    const float* eW2 = (const float*)d_in[5];
    const float* eb2 = (const float*)d_in[6];
    const float* nW1 = (const float*)d_in[7];
    const float* nb1 = (const float*)d_in[8];
    const float* nW2 = (const float*)d_in[9];
    const float* nb2 = (const float*)d_in[10];
    const float* fW  = (const float*)d_in[11];
    const float* fb  = (const float*)d_in[12];
    float* out = (float*)d_out;

    // ---- workspace carve-up (256B aligned): ~58.6 MB ----
    size_t off = 0;
    auto carve = [&](size_t bytes) {
        void* p = (char*)d_ws + off;
        off = (off + bytes + 255) & ~(size_t)255;
        return p;
    };
    float*     agg    = (float*)carve((size_t)N_NODES * H_NF * sizeof(float)); // 51.2 MB
    int*       perm   = (int*)  carve((size_t)N_EDGES * sizeof(int));          // 6.4 MB
    int*       hist   = (int*)  carve((size_t)N_NODES * sizeof(int));
    int*       starts = (int*)  carve((size_t)(N_NODES + 1) * sizeof(int));
    int*       cursor = (int*)  carve((size_t)N_NODES * sizeof(int));
    int*       bsum   = (int*)  carve((size_t)(NBLK + 1) * sizeof(int));
    _Float16*  w1h    = (_Float16*)carve((size_t)H_NF * K1P * sizeof(_Float16)); // 10 KB
    _Float16*  w2h    = (_Float16*)carve((size_t)H_NF * K2P * sizeof(_Float16)); // 34.8 KB
    size_t required = off;

    if (ws_size >= required) {
        prep_w1h<<<(H_NF * K1P + 255) / 256, 256, 0, stream>>>(eW1, w1h);
        prep_w2h<<<(H_NF * K2P + 255) / 256, 256, 0, stream>>>(eW2, w2h);
        hipMemsetAsync(agg, 0, (size_t)N_NODES * H_NF * sizeof(float), stream);
        hipMemsetAsync(hist, 0, (size_t)N_NODES * sizeof(int), stream);
        hist_kernel<<<(N_EDGES + 255) / 256, 256, 0, stream>>>(edge_index, hist);
        scan1_kernel<<<NBLK, SCAN_B, 0, stream>>>(hist, starts, bsum);
        scan2_kernel<<<1, 64, 0, stream>>>(bsum);
        scan3_kernel<<<(N_NODES + 255) / 256, 256, 0, stream>>>(starts, cursor, bsum);
        permute_kernel<<<(N_EDGES + 255) / 256, 256, 0, stream>>>(edge_index, cursor, perm);
        edge_mfma_kernel<<<N_EDGES / 64, 256, 0, stream>>>(
            node_feats, edge_index, edge_attr, w1h, eb1, w2h, eb2, perm, agg);
    } else {
        // fallback: fp32 atomic scatter (needs 51.3 MB)
        agg = (float*)d_ws;
        float* W2T_fb = (float*)((char*)d_ws + (size_t)N_NODES * H_NF * sizeof(float));
        transpose_w2<<<(H_NF * H_NF + 255) / 256, 256, 0, stream>>>(eW2, W2T_fb);
        hipMemsetAsync(agg, 0, (size_t)N_NODES * H_NF * sizeof(float), stream);
        edge_kernel_atomic<<<(N_EDGES + 255) / 256, 256, 0, stream>>>(
            node_feats, edge_index, edge_attr, eW1, eb1, W2T_fb, eb2, agg);
    }

    node_kernel1<<<(N_NODES + 255) / 256, 256, 0, stream>>>(node_feats, agg, nW1, nb1);
    node_kernel2<<<(N_NODES + 255) / 256, 256, 0, stream>>>(agg, nW2, nb2, fW, fb, out);
}

// Round 6
// 607.630 us; speedup vs baseline: 17.9737x; 1.5744x over previous
//
#include <hip/hip_runtime.h>

#define N_NODES 100000
#define N_EDGES 1600000
#define NODE_NF 11
#define EDGE_NF 4
#define H_NF 128
#define SCAN_B 1024
#define NBLK ((N_NODES + SCAN_B - 1) / SCAN_B)   // 98

// Edge-MLP input layout (halves): src@0..10, 0@11, dst@12..22, 0@23,
// attr@24..27, 0@28..31 (+don't-care to 40). K=32 MFMA window covers 0..31.
#define K1P 40    // Ain / w1h row stride (halves); 80 B rows -> 2-way banks only
#define K2P 136   // h / w2h row stride (halves); 272 B rows -> 2-way banks only
#define EFP 131   // ef row stride (floats); breaks the 4-way conflict
#define K1N 160   // node layer-1 padded K: nf@0..10, 0@11, agg@12..139, 0@140..159

typedef _Float16 half8 __attribute__((ext_vector_type(8)));
typedef float floatx4 __attribute__((ext_vector_type(4)));

__device__ inline half8 load8f(const float* p) {
    float4 x0 = *(const float4*)(p);
    float4 x1 = *(const float4*)(p + 4);
    half8 r;
    r[0]=(_Float16)x0.x; r[1]=(_Float16)x0.y; r[2]=(_Float16)x0.z; r[3]=(_Float16)x0.w;
    r[4]=(_Float16)x1.x; r[5]=(_Float16)x1.y; r[6]=(_Float16)x1.z; r[7]=(_Float16)x1.w;
    return r;
}
__device__ inline half8 zero8() {
    half8 z;
    #pragma unroll
    for (int j = 0; j < 8; ++j) z[j] = (_Float16)0.f;
    return z;
}

// ---------------------------------------------------------------------------
// Prep kernels
// ---------------------------------------------------------------------------
// node_feats fp32 [N][11] -> fp16 [N][12] (slot 11 = 0) for packed gather
__global__ __launch_bounds__(256)
void prep_nfh(const float* __restrict__ nf, _Float16* __restrict__ nfh) {
    int i = blockIdx.x * 256 + threadIdx.x;
    if (i < N_NODES * 12) {
        int n = i / 12, k = i - n * 12;
        nfh[i] = (k < NODE_NF) ? (_Float16)nf[(size_t)n * NODE_NF + k] : (_Float16)0.f;
    }
}

// eW1 -> fp16 n-major [128][40] with the src/0/dst/0/attr/0 K layout.
// e_in rows: 0..10 src, 11..21 dst, 22..25 attr.
// slots: 0..10 -> rows 0..10; 12..22 -> rows 11..21 (k-1); 24..27 -> rows 22..25 (k-2).
__global__ __launch_bounds__(256)
void prep_w1h(const float* __restrict__ eW1, _Float16* __restrict__ w1h) {
    int i = blockIdx.x * 256 + threadIdx.x;
    if (i < H_NF * K1P) {
        int n = i / K1P, k = i - n * K1P;
        float v = 0.f;
        if (k < 11)                 v = eW1[k * H_NF + n];
        else if (k >= 12 && k < 23) v = eW1[(k - 1) * H_NF + n];
        else if (k >= 24 && k < 28) v = eW1[(k - 2) * H_NF + n];   // FIXED: was k-4
        w1h[i] = (_Float16)v;
    }
}

// eW2 -> fp16 n-major [128][136]
__global__ __launch_bounds__(256)
void prep_w2h(const float* __restrict__ eW2, _Float16* __restrict__ w2h) {
    int i = blockIdx.x * 256 + threadIdx.x;
    if (i < H_NF * K2P) {
        int n = i / K2P, k = i - n * K2P;
        w2h[i] = (k < H_NF) ? (_Float16)eW2[k * H_NF + n] : (_Float16)0.f;
    }
}

// nW1 -> fp16 n-major [128][160] with nf@0..10, 0@11, agg@12..139 layout
__global__ __launch_bounds__(256)
void prep_w1nh(const float* __restrict__ nW1, _Float16* __restrict__ w1nh) {
    int i = blockIdx.x * 256 + threadIdx.x;
    if (i < H_NF * K1N) {
        int n = i / K1N, k = i - n * K1N;
        float v = 0.f;
        if (k < 11)                  v = nW1[k * H_NF + n];
        else if (k >= 12 && k < 140) v = nW1[(k - 1) * H_NF + n];
        w1nh[i] = (_Float16)v;
    }
}

// W23 = nW2 @ fW  (fc_emb folded into node layer 2 — no ReLU between, exact),
// stored fp16 n-major [16][136] (rows 4..15 zero). Also b23 = nb2@fW + fb.
__global__ __launch_bounds__(256)
void prep_w23(const float* __restrict__ nW2, const float* __restrict__ fW,
              const float* __restrict__ nb2, const float* __restrict__ fb,
              _Float16* __restrict__ w23h, float* __restrict__ b23) {
    int i = blockIdx.x * 256 + threadIdx.x;
    if (i < 16 * K2P) {
        int n = i / K2P, k = i - n * K2P;
        float v = 0.f;
        if (n < 4 && k < H_NF) {
            for (int j = 0; j < H_NF; ++j) v += nW2[k * H_NF + j] * fW[j * 4 + n];
        }
        w23h[i] = (_Float16)v;
    } else if (i < 16 * K2P + 4) {
        int o = i - 16 * K2P;
        float v = fb[o];
        for (int j = 0; j < H_NF; ++j) v += nb2[j] * fW[j * 4 + o];
        b23[o] = v;
    }
}

// fallback-path prep
__global__ __launch_bounds__(256)
void transpose_w2(const float* __restrict__ W, float* __restrict__ WT) {
    int i = blockIdx.x * 256 + threadIdx.x;
    if (i < H_NF * H_NF) {
        int k = i >> 7, j = i & (H_NF - 1);
        WT[j * H_NF + k] = W[i];
    }
}

// ---------------------------------------------------------------------------
// Counting sort of edges by row. hist -> scan -> permute.
// ---------------------------------------------------------------------------
__global__ __launch_bounds__(256)
void hist_kernel(const int* __restrict__ edge_index, int* hist) {
    int e = blockIdx.x * 256 + threadIdx.x;
    if (e < N_EDGES) atomicAdd(&hist[edge_index[e]], 1);
}

__global__ __launch_bounds__(SCAN_B)
void scan1_kernel(const int* __restrict__ hist, int* starts, int* bsum) {
    __shared__ int buf[SCAN_B];
    int i = blockIdx.x * SCAN_B + threadIdx.x;
    int v = (i < N_NODES) ? hist[i] : 0;
    buf[threadIdx.x] = v;
    __syncthreads();
    for (int off = 1; off < SCAN_B; off <<= 1) {
        int t = (threadIdx.x >= off) ? buf[threadIdx.x - off] : 0;
        __syncthreads();
        buf[threadIdx.x] += t;
        __syncthreads();
    }
    if (i < N_NODES) starts[i] = buf[threadIdx.x] - v;
    if (threadIdx.x == SCAN_B - 1) bsum[blockIdx.x] = buf[SCAN_B - 1];
}

__global__ void scan2_kernel(int* bsum) {
    if (threadIdx.x == 0 && blockIdx.x == 0) {
        int run = 0;
        for (int b = 0; b < NBLK; ++b) { int t = bsum[b]; bsum[b] = run; run += t; }
        bsum[NBLK] = run;
    }
}

__global__ __launch_bounds__(256)
void scan3_kernel(int* starts, int* cursor, const int* __restrict__ bsum) {
    int i = blockIdx.x * 256 + threadIdx.x;
    if (i < N_NODES) {
        int s = starts[i] + bsum[i / SCAN_B];
        starts[i] = s;
        cursor[i] = s;
    }
    if (i == 0) starts[N_NODES] = bsum[NBLK];
}

__global__ __launch_bounds__(256)
void permute_kernel(const int* __restrict__ edge_index, int* cursor, int* perm) {
    int e = blockIdx.x * 256 + threadIdx.x;
    if (e < N_EDGES) {
        int pos = atomicAdd(&cursor[edge_index[e]], 1);
        perm[pos] = e;
    }
}

// ---------------------------------------------------------------------------
// Edge MLP, persistent + wave-independent.
// Block = 4 waves; weights staged to LDS once (single barrier), then each
// wave loops over 16-edge windows with a private LDS arena — NO barriers in
// the loop (same-wave LDS ordering is in-order; proven by R4's Hs path).
// Per window: packed fp16 gather -> 8 MFMA (L1) -> h via LDS -> 32 MFMA (L2)
// -> ef tile -> serial segmented reduction (16 iters) -> sparse atomics.
// ---------------------------------------------------------------------------
#define E_W1      0                       // 128*40*2  = 10240
#define E_W2      10240                   // 128*136*2 = 34816 -> ends 45056
#define E_ARENA   45056
#define E_ARENA_SZ 8448                   // Ain@0(1280) Hs@1280(4352) ef@0(8384) rows@8384(64)
#define E_TOTAL   (E_ARENA + 4 * E_ARENA_SZ)   // 78848 -> 2 blocks/CU

__global__ __launch_bounds__(256, 2)
void edge_mfma_kernel(const _Float16* __restrict__ nfh,
                      const int*   __restrict__ edge_index,
                      const float* __restrict__ edge_attr,
                      const _Float16* __restrict__ w1h,
                      const float* __restrict__ eb1,
                      const _Float16* __restrict__ w2h,
                      const float* __restrict__ eb2,
                      const int*   __restrict__ perm,
                      float* agg)   // [N_NODES][H_NF]
{
    __shared__ __align__(16) char smem[E_TOTAL];
    _Float16* W1s = (_Float16*)(smem + E_W1);
    _Float16* W2s = (_Float16*)(smem + E_W2);
    int t = threadIdx.x;
    {
        const float4* g1 = (const float4*)w1h;   // 10240/16 = 640
        float4* s1 = (float4*)W1s;
        for (int i = t; i < 640; i += 256) s1[i] = g1[i];
        const float4* g2 = (const float4*)w2h;   // 34816/16 = 2176
        float4* s2 = (float4*)W2s;
        for (int i = t; i < 2176; i += 256) s2[i] = g2[i];
    }
    __syncthreads();   // the only barrier

    int wv = t >> 6, lane = t & 63;
    char* arena = smem + E_ARENA + wv * E_ARENA_SZ;
    _Float16* Ain  = (_Float16*)arena;
    _Float16* Hs   = (_Float16*)(arena + 1280);
    float*    efS  = (float*)arena;              // aliases Ain+Hs (per-wave lifetime)
    int*      rowsS = (int*)(arena + 8384);

    int m = lane & 15, quad = lane >> 4;
    int el = lane & 15, grp = lane >> 4;
    _Float16* arow = Ain + el * K1P;

    // per-lane biases (tile*16+m), hoisted out of the loop
    float b1v[8], b2v[8];
    #pragma unroll
    for (int tile = 0; tile < 8; ++tile) {
        b1v[tile] = eb1[tile * 16 + m];
        b2v[tile] = eb2[tile * 16 + m];
    }

    const int nwin = N_EDGES / 16;   // 100000
    for (int win = blockIdx.x * 4 + wv; win < nwin; win += gridDim.x * 4) {
        int e = perm[win * 16 + el];   // 16 unique addrs, dup x4 -> broadcast

        // ---- gather: packed fp16 rows -> Ain ----
        if (grp < 2) {
            int node = edge_index[grp * N_EDGES + e];
            const int2* p = (const int2*)(nfh + (size_t)node * 12);
            int2 x0 = p[0];                       // halves 0..3
            int2 x1 = p[1];                       // halves 4..7
            int2 x2 = p[2];                       // halves 8..11 (11 = 0)
            char* dst = (char*)(arow + grp * 12); // byte 0 or 24, both 8-aligned
            *(int2*)(dst)      = x0;
            *(int2*)(dst + 8)  = x1;
            *(int2*)(dst + 16) = x2;
        } else if (grp == 2) {
            float4 a4 = ((const float4*)edge_attr)[e];
            arow[24] = (_Float16)a4.x; arow[25] = (_Float16)a4.y;
            arow[26] = (_Float16)a4.z; arow[27] = (_Float16)a4.w;
        } else {
            rowsS[el] = edge_index[e];
            *(int2*)((char*)arow + 56) = make_int2(0, 0);   // halves 28..31 = 0
        }

        // ---- layer 1: 26(pad32) -> 128 ----
        half8 a1 = *(const half8*)(Ain + m * K1P + quad * 8);
        #pragma unroll
        for (int tile = 0; tile < 8; ++tile) {
            half8 b = *(const half8*)(W1s + (tile * 16 + m) * K1P + quad * 8);
            floatx4 c = {0.f, 0.f, 0.f, 0.f};
            c = __builtin_amdgcn_mfma_f32_16x16x32_f16(a1, b, c, 0, 0, 0);
            int n = tile * 16 + m;
            #pragma unroll
            for (int r = 0; r < 4; ++r)
                Hs[(quad * 4 + r) * K2P + n] = (_Float16)fmaxf(c[r] + b1v[tile], 0.f);
        }

        // ---- layer 2: 128 -> 128 ----
        half8 a2[4];
        #pragma unroll
        for (int ks = 0; ks < 4; ++ks)
            a2[ks] = *(const half8*)(Hs + m * K2P + ks * 32 + quad * 8);

        float vals[32];
        #pragma unroll
        for (int tile = 0; tile < 8; ++tile) {
            floatx4 c = {0.f, 0.f, 0.f, 0.f};
            #pragma unroll
            for (int ks = 0; ks < 4; ++ks) {
                half8 b = *(const half8*)(W2s + (tile * 16 + m) * K2P + ks * 32 + quad * 8);
                c = __builtin_amdgcn_mfma_f32_16x16x32_f16(a2[ks], b, c, 0, 0, 0);
            }
            #pragma unroll
            for (int r = 0; r < 4; ++r)
                vals[tile * 4 + r] = fmaxf(c[r] + b2v[tile], 0.f);
        }

        // ---- ef tile (overlays Ain/Hs — same-wave in-order LDS) ----
        #pragma unroll
        for (int tile = 0; tile < 8; ++tile)
            #pragma unroll
            for (int r = 0; r < 4; ++r)
                efS[(quad * 4 + r) * EFP + tile * 16 + m] = vals[tile * 4 + r];

        // ---- segmented reduction over 16 sorted edges; 2 features/lane ----
        int f = lane;
        int cur = rowsS[0];
        float acc0 = efS[f], acc1 = efS[64 + f];
        #pragma unroll 1
        for (int i = 1; i < 16; ++i) {
            int r = rowsS[i];                       // wave-uniform
            float v0 = efS[i * EFP + f];
            float v1 = efS[i * EFP + 64 + f];
            if (r != cur) {                         // wave-uniform branch
                unsafeAtomicAdd(&agg[(size_t)cur * H_NF + f], acc0);
                unsafeAtomicAdd(&agg[(size_t)cur * H_NF + 64 + f], acc1);
                acc0 = v0; acc1 = v1; cur = r;
            } else { acc0 += v0; acc1 += v1; }
        }
        unsafeAtomicAdd(&agg[(size_t)cur * H_NF + f], acc0);
        unsafeAtomicAdd(&agg[(size_t)cur * H_NF + 64 + f], acc1);
    }
}

// ---------------------------------------------------------------------------
// Fused node pipeline: n_h = relu([nf, agg] @ nW1 + nb1); out = n_h @ W23 + b23.
// Block = 4 waves x 16 nodes. A-frags built from agg/nf in registers (fp16),
// h through per-wave LDS, single barrier (weight staging).
// ---------------------------------------------------------------------------
#define N_W1    0                         // 128*160*2 = 40960
#define N_W23   40960                     // 16*136*2  = 4352 -> 45312
#define N_HS    45312                     // 4 x 4352 -> total 62720 -> 2 blocks/CU

__global__ __launch_bounds__(256, 2)
void node_mfma_kernel(const float* __restrict__ node_feats,
                      const float* __restrict__ agg,
                      const _Float16* __restrict__ w1nh,
                      const float* __restrict__ nb1,
                      const _Float16* __restrict__ w23h,
                      const float* __restrict__ b23,
                      float* __restrict__ out)
{
    __shared__ __align__(16) char smem[N_HS + 4 * 4352];
    _Float16* W1N  = (_Float16*)(smem + N_W1);
    _Float16* W23s = (_Float16*)(smem + N_W23);
    int t = threadIdx.x;
    {
        const float4* g1 = (const float4*)w1nh;   // 40960/16 = 2560
        float4* s1 = (float4*)W1N;
        for (int i = t; i < 2560; i += 256) s1[i] = g1[i];
        const float4* g2 = (const float4*)w23h;   // 4352/16 = 272
        float4* s2 = (float4*)W23s;
        for (int i = t; i < 272; i += 256) s2[i] = g2[i];
    }
    __syncthreads();

    int wv = t >> 6, lane = t & 63;
    int m = lane & 15, quad = lane >> 4;
    int nb = (blockIdx.x * 4 + wv) * 16;
    if (nb >= N_NODES) return;

    int nodeA = nb + m;
    if (nodeA >= N_NODES) nodeA = N_NODES - 1;
    const float* ag  = agg + (size_t)nodeA * H_NF;
    const float* nfp = node_feats + (size_t)nodeA * NODE_NF;

    // A-fragments: k-layout nf@0..10, 0@11, agg@12..139, 0@140..159
    half8 afr[5];
    if (quad == 0) {
        half8 r;
        #pragma unroll
        for (int j = 0; j < 8; ++j) r[j] = (_Float16)nfp[j];
        afr[0] = r;
        afr[4] = load8f(ag + 116);
    } else if (quad == 1) {
        half8 r;
        r[0] = (_Float16)nfp[8]; r[1] = (_Float16)nfp[9];
        r[2] = (_Float16)nfp[10]; r[3] = (_Float16)0.f;
        float4 x = *(const float4*)(ag);
        r[4] = (_Float16)x.x; r[5] = (_Float16)x.y;
        r[6] = (_Float16)x.z; r[7] = (_Float16)x.w;
        afr[0] = r;
        float4 y = *(const float4*)(ag + 124);
        half8 s = zero8();
        s[0] = (_Float16)y.x; s[1] = (_Float16)y.y;
        s[2] = (_Float16)y.z; s[3] = (_Float16)y.w;
        afr[4] = s;
    } else if (quad == 2) {
        afr[0] = load8f(ag + 4);
        afr[4] = zero8();
    } else {
        afr[0] = load8f(ag + 12);
        afr[4] = zero8();
    }
    afr[1] = load8f(ag + 20 + 8 * quad);
    afr[2] = load8f(ag + 52 + 8 * quad);
    afr[3] = load8f(ag + 84 + 8 * quad);

    _Float16* HsW = (_Float16*)(smem + N_HS + wv * 4352);

    // layer 1: 139(pad160) -> 128, relu
    #pragma unroll
    for (int tile = 0; tile < 8; ++tile) {
        floatx4 c = {0.f, 0.f, 0.f, 0.f};
        #pragma unroll
        for (int ks = 0; ks < 5; ++ks) {
            half8 b = *(const half8*)(W1N + (tile * 16 + m) * K1N + ks * 32 + quad * 8);
            c = __builtin_amdgcn_mfma_f32_16x16x32_f16(afr[ks], b, c, 0, 0, 0);
        }
        float bv = nb1[tile * 16 + m];
        #pragma unroll
        for (int r = 0; r < 4; ++r)
            HsW[(quad * 4 + r) * K2P + tile * 16 + m] = (_Float16)fmaxf(c[r] + bv, 0.f);
    }

    // layer 2 (+ folded fc_emb): 128 -> 4
    half8 a2[4];
    #pragma unroll
    for (int ks = 0; ks < 4; ++ks)
        a2[ks] = *(const half8*)(HsW + m * K2P + ks * 32 + quad * 8);
    floatx4 c23 = {0.f, 0.f, 0.f, 0.f};
    #pragma unroll
    for (int ks = 0; ks < 4; ++ks) {
        half8 b = *(const half8*)(W23s + m * K2P + ks * 32 + quad * 8);
        c23 = __builtin_amdgcn_mfma_f32_16x16x32_f16(a2[ks], b, c23, 0, 0, 0);
    }
    if (m < 4) {
        float bv = b23[m];
        #pragma unroll
        for (int r = 0; r < 4; ++r) {
            int node = nb + quad * 4 + r;
            if (node < N_NODES) out[node * 4 + m] = c23[r] + bv;
        }
    }
}

// ---------------------------------------------------------------------------
// Fallback path (ws too small): fp32 atomic scatter + fp32 node kernels.
// ---------------------------------------------------------------------------
__global__ __launch_bounds__(256)
void edge_kernel_atomic(const float* __restrict__ node_feats,
                        const int*   __restrict__ edge_index,
                        const float* __restrict__ edge_attr,
                        const float* __restrict__ eW1,
                        const float* __restrict__ eb1,
                        const float* __restrict__ W2T,
                        const float* __restrict__ eb2,
                        float* agg)
{
    int e = blockIdx.x * 256 + threadIdx.x;
    if (e >= N_EDGES) return;
    int row = edge_index[e];
    int col = edge_index[N_EDGES + e];
    float h[H_NF];
    #pragma unroll
    for (int j = 0; j < H_NF; ++j) h[j] = eb1[j];
    const float* srcp = node_feats + (size_t)row * NODE_NF;
    #pragma unroll 1
    for (int k = 0; k < NODE_NF; ++k) {
        float x = srcp[k];
        const float* w = eW1 + k * H_NF;
        #pragma unroll
        for (int j = 0; j < H_NF; ++j) h[j] = fmaf(x, w[j], h[j]);
    }
    const float* dstp = node_feats + (size_t)col * NODE_NF;
    #pragma unroll 1
    for (int k = 0; k < NODE_NF; ++k) {
        float x = dstp[k];
        const float* w = eW1 + (NODE_NF + k) * H_NF;
        #pragma unroll
        for (int j = 0; j < H_NF; ++j) h[j] = fmaf(x, w[j], h[j]);
    }
    float4 at = ((const float4*)edge_attr)[e];
    float av[EDGE_NF] = {at.x, at.y, at.z, at.w};
    #pragma unroll
    for (int k = 0; k < EDGE_NF; ++k) {
        float x = av[k];
        const float* w = eW1 + (2 * NODE_NF + k) * H_NF;
        #pragma unroll
        for (int j = 0; j < H_NF; ++j) h[j] = fmaf(x, w[j], h[j]);
    }
    #pragma unroll
    for (int j = 0; j < H_NF; ++j) h[j] = fmaxf(h[j], 0.f);
    #pragma unroll 1
    for (int j0 = 0; j0 < H_NF; j0 += 8) {
        float acc[8];
        #pragma unroll
        for (int jj = 0; jj < 8; ++jj) acc[jj] = eb2[j0 + jj];
        #pragma unroll
        for (int k = 0; k < H_NF; ++k) {
            float x = h[k];
            #pragma unroll
            for (int jj = 0; jj < 8; ++jj)
                acc[jj] = fmaf(x, W2T[(j0 + jj) * H_NF + k], acc[jj]);
        }
        #pragma unroll
        for (int jj = 0; jj < 8; ++jj)
            unsafeAtomicAdd(&agg[(size_t)row * H_NF + j0 + jj], fmaxf(acc[jj], 0.f));
    }
}

__global__ __launch_bounds__(256)
void node_kernel1(const float* __restrict__ node_feats, float* agg_nh,
                  const float* __restrict__ nW1, const float* __restrict__ nb1)
{
    int n = blockIdx.x * 256 + threadIdx.x;
    if (n >= N_NODES) return;
    float acc[H_NF];
    #pragma unroll
    for (int j = 0; j < H_NF; ++j) acc[j] = nb1[j];
    const float* nfp = node_feats + (size_t)n * NODE_NF;
    #pragma unroll 1
    for (int k = 0; k < NODE_NF; ++k) {
        float x = nfp[k];
        const float* w = nW1 + k * H_NF;
        #pragma unroll
        for (int j = 0; j < H_NF; ++j) acc[j] = fmaf(x, w[j], acc[j]);
    }
    const float4* ap = (const float4*)(agg_nh + (size_t)n * H_NF);
    #pragma unroll 1
    for (int k4 = 0; k4 < H_NF / 4; ++k4) {
        float4 x = ap[k4];
        const float* w0 = nW1 + (NODE_NF + k4 * 4 + 0) * H_NF;
        const float* w1 = nW1 + (NODE_NF + k4 * 4 + 1) * H_NF;
        const float* w2 = nW1 + (NODE_NF + k4 * 4 + 2) * H_NF;
        const float* w3 = nW1 + (NODE_NF + k4 * 4 + 3) * H_NF;
        #pragma unroll
        for (int j = 0; j < H_NF; ++j) {
            acc[j] = fmaf(x.x, w0[j], acc[j]);
            acc[j] = fmaf(x.y, w1[j], acc[j]);
            acc[j] = fmaf(x.z, w2[j], acc[j]);
            acc[j] = fmaf(x.w, w3[j], acc[j]);
        }
    }
    float* op = agg_nh + (size_t)n * H_NF;
    #pragma unroll
    for (int j4 = 0; j4 < H_NF / 4; ++j4) {
        float4 o = make_float4(fmaxf(acc[j4*4+0], 0.f), fmaxf(acc[j4*4+1], 0.f),
                               fmaxf(acc[j4*4+2], 0.f), fmaxf(acc[j4*4+3], 0.f));
        ((float4*)op)[j4] = o;
    }
}

__global__ __launch_bounds__(256)
void node_kernel2(const float* __restrict__ nh, const float* __restrict__ nW2,
                  const float* __restrict__ nb2, const float* __restrict__ fW,
                  const float* __restrict__ fb, float* __restrict__ out)
{
    int n = blockIdx.x * 256 + threadIdx.x;
    if (n >= N_NODES) return;
    float acc[H_NF];
    #pragma unroll
    for (int j = 0; j < H_NF; ++j) acc[j] = nb2[j];
    const float4* hp = (const float4*)(nh + (size_t)n * H_NF);
    #pragma unroll 1
    for (int k4 = 0; k4 < H_NF / 4; ++k4) {
        float4 x = hp[k4];
        const float* w0 = nW2 + (k4 * 4 + 0) * H_NF;
        const float* w1 = nW2 + (k4 * 4 + 1) * H_NF;
        const float* w2 = nW2 + (k4 * 4 + 2) * H_NF;
        const float* w3 = nW2 + (k4 * 4 + 3) * H_NF;
        #pragma unroll
        for (int j = 0; j < H_NF; ++j) {
            acc[j] = fmaf(x.x, w0[j], acc[j]);
            acc[j] = fmaf(x.y, w1[j], acc[j]);
            acc[j] = fmaf(x.z, w2[j], acc[j]);
            acc[j] = fmaf(x.w, w3[j], acc[j]);
        }
    }
    float o0 = fb[0], o1 = fb[1], o2 = fb[2], o3 = fb[3];
    #pragma unroll
    for (int j = 0; j < H_NF; ++j) {
        o0 = fmaf(acc[j], fW[j * 4 + 0], o0);
        o1 = fmaf(acc[j], fW[j * 4 + 1], o1);
        o2 = fmaf(acc[j], fW[j * 4 + 2], o2);
        o3 = fmaf(acc[j], fW[j * 4 + 3], o3);
    }
    ((float4*)out)[n] = make_float4(o0, o1, o2, o3);
}

extern "C" void kernel_launch(void* const* d_in, const int* in_sizes, int n_in,
                              void* d_out, int out_size, void* d_ws, size_t ws_size,
                              hipStream_t stream)
{
    const float* node_feats = (const float*)d_in[0];
    const int*   edge_index = (const int*)d_in[1];
    const float* edge_attr  = (const float*)d_in[2];
    const float* eW1 = (const float*)d_in[3];
    const float* eb1 = (const float*)d_in[4];
    const float* eW2 = (const float*)d_in[5];
    const float* eb2 = (const float*)d_in[6];
    const float* nW1 = (const float*)d_in[7];
    const float* nb1 = (const float*)d_in[8];
    const float* nW2 = (const float*)d_in[9];
    const float* nb2 = (const float*)d_in[10];
    const float* fW  = (const float*)d_in[11];
    const float* fb  = (const float*)d_in[12];
    float* out = (float*)d_out;

    // ---- workspace carve-up (256B aligned): ~60.9 MB ----
    size_t off = 0;
    auto carve = [&](size_t bytes) {
        void* p = (char*)d_ws + off;
        off = (off + bytes + 255) & ~(size_t)255;
        return p;
    };
    float*     agg    = (float*)carve((size_t)N_NODES * H_NF * sizeof(float)); // 51.2 MB
    int*       perm   = (int*)  carve((size_t)N_EDGES * sizeof(int));          // 6.4 MB
    int*       hist   = (int*)  carve((size_t)N_NODES * sizeof(int));
    int*       starts = (int*)  carve((size_t)(N_NODES + 1) * sizeof(int));
    int*       cursor = (int*)  carve((size_t)N_NODES * sizeof(int));
    int*       bsum   = (int*)  carve((size_t)(NBLK + 1) * sizeof(int));
    _Float16*  nfh    = (_Float16*)carve((size_t)N_NODES * 12 * sizeof(_Float16)); // 2.4 MB
    _Float16*  w1h    = (_Float16*)carve((size_t)H_NF * K1P * sizeof(_Float16));
    _Float16*  w2h    = (_Float16*)carve((size_t)H_NF * K2P * sizeof(_Float16));
    _Float16*  w1nh   = (_Float16*)carve((size_t)H_NF * K1N * sizeof(_Float16));
    _Float16*  w23h   = (_Float16*)carve((size_t)16 * K2P * sizeof(_Float16));
    float*     b23    = (float*)carve(4 * sizeof(float));
    size_t required = off;

    if (ws_size >= required) {
        prep_nfh <<<(N_NODES * 12 + 255) / 256, 256, 0, stream>>>(node_feats, nfh);
        prep_w1h <<<(H_NF * K1P + 255) / 256, 256, 0, stream>>>(eW1, w1h);
        prep_w2h <<<(H_NF * K2P + 255) / 256, 256, 0, stream>>>(eW2, w2h);
        prep_w1nh<<<(H_NF * K1N + 255) / 256, 256, 0, stream>>>(nW1, w1nh);
        prep_w23 <<<(16 * K2P + 4 + 255) / 256, 256, 0, stream>>>(nW2, fW, nb2, fb, w23h, b23);
        hipMemsetAsync(agg, 0, (size_t)N_NODES * H_NF * sizeof(float), stream);
        hipMemsetAsync(hist, 0, (size_t)N_NODES * sizeof(int), stream);
        hist_kernel<<<(N_EDGES + 255) / 256, 256, 0, stream>>>(edge_index, hist);
        scan1_kernel<<<NBLK, SCAN_B, 0, stream>>>(hist, starts, bsum);
        scan2_kernel<<<1, 64, 0, stream>>>(bsum);
        scan3_kernel<<<(N_NODES + 255) / 256, 256, 0, stream>>>(starts, cursor, bsum);
        permute_kernel<<<(N_EDGES + 255) / 256, 256, 0, stream>>>(edge_index, cursor, perm);
        edge_mfma_kernel<<<1024, 256, 0, stream>>>(
            nfh, edge_index, edge_attr, w1h, eb1, w2h, eb2, perm, agg);
        node_mfma_kernel<<<(N_NODES + 63) / 64, 256, 0, stream>>>(
            node_feats, agg, w1nh, nb1, w23h, b23, out);
    } else {
        // fallback: fp32 atomic scatter + fp32 node kernels (needs 51.3 MB)
        float* agg_fb = (float*)d_ws;
        float* W2T_fb = (float*)((char*)d_ws + (size_t)N_NODES * H_NF * sizeof(float));
        transpose_w2<<<(H_NF * H_NF + 255) / 256, 256, 0, stream>>>(eW2, W2T_fb);
        hipMemsetAsync(agg_fb, 0, (size_t)N_NODES * H_NF * sizeof(float), stream);
        edge_kernel_atomic<<<(N_EDGES + 255) / 256, 256, 0, stream>>>(
            node_feats, edge_index, edge_attr, eW1, eb1, W2T_fb, eb2, agg_fb);
        node_kernel1<<<(N_NODES + 255) / 256, 256, 0, stream>>>(node_feats, agg_fb, nW1, nb1);
        node_kernel2<<<(N_NODES + 255) / 256, 256, 0, stream>>>(agg_fb, nW2, nb2, fW, fb, out);
    }
}